// Round 1
// baseline (436.735 us; speedup 1.0000x reference)
//
#include <hip/hip_runtime.h>
#include <hip/hip_bf16.h>
#include <math.h>

// Problem constants (validated against in_sizes at launch).
#define FDIM 128     // in/hid feature dim
#define ODIM 40      // output classes

// ---------------------------------------------------------------------------
// 1) count in-degrees (dst side) with int atomics
// ---------------------------------------------------------------------------
__global__ void count_edges_k(const int* __restrict__ dst, int* __restrict__ count, int E) {
    int e = blockIdx.x * blockDim.x + threadIdx.x;
    if (e < E) atomicAdd(&count[dst[e]], 1);
}

// ---------------------------------------------------------------------------
// 2) single-block exclusive scan -> rowptr/cursor; dinv = rsqrt(count+1)
// ---------------------------------------------------------------------------
__global__ __launch_bounds__(1024) void scan_deg_k(const int* __restrict__ count,
                                                   int* __restrict__ rowptr,
                                                   int* __restrict__ cursor,
                                                   float* __restrict__ dinv, int n) {
    __shared__ int buf[1024];
    __shared__ int carry_s;
    int tid = threadIdx.x;
    if (tid == 0) carry_s = 0;
    __syncthreads();
    for (int base = 0; base < n; base += 1024) {
        int i = base + tid;
        int c = (i < n) ? count[i] : 0;
        if (i < n) dinv[i] = rsqrtf((float)(c + 1));
        buf[tid] = c;
        __syncthreads();
        // Hillis-Steele inclusive scan over 1024
        for (int off = 1; off < 1024; off <<= 1) {
            int v = (tid >= off) ? buf[tid - off] : 0;
            __syncthreads();
            if (tid >= off) buf[tid] += v;
            __syncthreads();
        }
        int incl = buf[tid];
        int excl = incl - c;
        int carry = carry_s;
        if (i < n) {
            rowptr[i] = carry + excl;
            cursor[i] = carry + excl;
        }
        __syncthreads();
        if (tid == 1023) carry_s = carry + incl;
        __syncthreads();
    }
    if (tid == 0) rowptr[n] = carry_s;
}

// ---------------------------------------------------------------------------
// 3) fill CSR: src ids grouped by dst
// ---------------------------------------------------------------------------
__global__ void fill_csr_k(const int* __restrict__ src, const int* __restrict__ dst,
                           int* __restrict__ cursor, int* __restrict__ csr_src, int E) {
    int e = blockIdx.x * blockDim.x + threadIdx.x;
    if (e < E) {
        int d = dst[e];
        int p = atomicAdd(&cursor[d], 1);
        csr_src[p] = src[e];
    }
}

// ---------------------------------------------------------------------------
// 4) SGEMM: C[M,128] = (A[M,128] @ B[128,128]) * dinv[row]
//    64x128 tile per 256-thread block, BK=16, 4x8 microtile per thread.
// ---------------------------------------------------------------------------
__global__ __launch_bounds__(256) void sgemm128_scale_k(const float* __restrict__ A,
                                                        const float* __restrict__ B,
                                                        const float* __restrict__ dinv,
                                                        float* __restrict__ C, int M) {
    __shared__ float As[16][68];    // transposed A tile: As[k][row], pad to 68
    __shared__ float Bs[16][132];   // Bs[k][n], pad to 132

    const int tid = threadIdx.x;
    const int row0 = blockIdx.x * 64;
    const int ty = tid >> 4;        // 0..15 -> 4 rows each
    const int tx = tid & 15;        // 0..15 -> 8 cols each
    const int arow = tid >> 2;      // 0..63 (A-tile load row)
    const int akq = tid & 3;        // float4 chunk in k-slab

    float acc[4][8];
#pragma unroll
    for (int i = 0; i < 4; ++i)
#pragma unroll
        for (int j = 0; j < 8; ++j) acc[i][j] = 0.f;

    for (int k0 = 0; k0 < 128; k0 += 16) {
        // stage A (64x16) transposed
        float4 av = make_float4(0.f, 0.f, 0.f, 0.f);
        int grow = row0 + arow;
        if (grow < M) av = *(const float4*)&A[(size_t)grow * 128 + k0 + akq * 4];
        As[akq * 4 + 0][arow] = av.x;
        As[akq * 4 + 1][arow] = av.y;
        As[akq * 4 + 2][arow] = av.z;
        As[akq * 4 + 3][arow] = av.w;
        // stage B (16x128): 512 float4s, 2 per thread
#pragma unroll
        for (int t = 0; t < 2; ++t) {
            int f = tid * 2 + t;
            int bk = f >> 5, bn = f & 31;
            float4 bv = *(const float4*)&B[(size_t)(k0 + bk) * 128 + bn * 4];
            *(float4*)&Bs[bk][bn * 4] = bv;
        }
        __syncthreads();
#pragma unroll
        for (int k = 0; k < 16; ++k) {
            float4 a4 = *(float4*)&As[k][ty * 4];
            float4 b0 = *(float4*)&Bs[k][tx * 8];
            float4 b1 = *(float4*)&Bs[k][tx * 8 + 4];
            float a[4] = {a4.x, a4.y, a4.z, a4.w};
            float b[8] = {b0.x, b0.y, b0.z, b0.w, b1.x, b1.y, b1.z, b1.w};
#pragma unroll
            for (int i = 0; i < 4; ++i)
#pragma unroll
                for (int j = 0; j < 8; ++j) acc[i][j] = fmaf(a[i], b[j], acc[i][j]);
        }
        __syncthreads();
    }
#pragma unroll
    for (int i = 0; i < 4; ++i) {
        int row = row0 + ty * 4 + i;
        if (row < M) {
            float sc = dinv[row];
            float4 o0 = make_float4(acc[i][0] * sc, acc[i][1] * sc, acc[i][2] * sc, acc[i][3] * sc);
            float4 o1 = make_float4(acc[i][4] * sc, acc[i][5] * sc, acc[i][6] * sc, acc[i][7] * sc);
            *(float4*)&C[(size_t)row * 128 + tx * 8] = o0;
            *(float4*)&C[(size_t)row * 128 + tx * 8 + 4] = o1;
        }
    }
}

// ---------------------------------------------------------------------------
// 5) aggregate: out[d,c] = act( dinv[d]*(g[d,c] + sum_{s in N(d)} g[s,c]) + b[c] )
//    one block (128 threads) per dst node; coalesced row gathers.
// ---------------------------------------------------------------------------
template <bool RELU>
__global__ __launch_bounds__(128) void aggregate_k(const float* __restrict__ g,
                                                   const float* __restrict__ dinv,
                                                   const int* __restrict__ rowptr,
                                                   const int* __restrict__ csr_src,
                                                   const float* __restrict__ bias,
                                                   float* __restrict__ out, int n) {
    int d = blockIdx.x;
    int c = threadIdx.x;
    float acc = g[(size_t)d * 128 + c];  // self-loop term
    int e = rowptr[d], end = rowptr[d + 1];
    for (; e + 1 < end; e += 2) {
        int s0 = csr_src[e];
        int s1 = csr_src[e + 1];
        float v0 = g[(size_t)s0 * 128 + c];
        float v1 = g[(size_t)s1 * 128 + c];
        acc += v0 + v1;
    }
    if (e < end) {
        int s0 = csr_src[e];
        acc += g[(size_t)s0 * 128 + c];
    }
    float v = fmaf(dinv[d], acc, bias[c]);
    if (RELU) v = fmaxf(v, 0.f);
    out[(size_t)d * 128 + c] = v;
}

// ---------------------------------------------------------------------------
// 6) logits = x_emb @ Wl + bl; log_softmax over 40 cols.
//    32 rows per 256-thread block; 8 lanes per row, 5 cols per lane.
// ---------------------------------------------------------------------------
__global__ __launch_bounds__(256) void logits_lsm_k(const float* __restrict__ xe,
                                                    const float* __restrict__ Wl,
                                                    const float* __restrict__ bl,
                                                    float* __restrict__ out, int M) {
    __shared__ float sW[128 * 40];
    __shared__ float sX[32][132];
    __shared__ float sB[40];
    const int tid = threadIdx.x;
    const int row0 = blockIdx.x * 32;

    for (int i = tid; i < (128 * 40) / 4; i += 256)
        ((float4*)sW)[i] = ((const float4*)Wl)[i];
    if (tid < 40) sB[tid] = bl[tid];
    for (int i = tid; i < 32 * 32; i += 256) {  // 1024 float4s
        int r = i >> 5, cq = i & 31;
        float4 v = make_float4(0.f, 0.f, 0.f, 0.f);
        if (row0 + r < M) v = *(const float4*)&xe[(size_t)(row0 + r) * 128 + cq * 4];
        *(float4*)&sX[r][cq * 4] = v;
    }
    __syncthreads();

    const int g = tid >> 3;  // local row 0..31
    const int l = tid & 7;   // lane-in-row
    const int row = row0 + g;
    float acc[5] = {0.f, 0.f, 0.f, 0.f, 0.f};
    for (int k = 0; k < 128; ++k) {
        float xv = sX[g][k];
        const float* w = &sW[k * 40 + l * 5];
#pragma unroll
        for (int j = 0; j < 5; ++j) acc[j] = fmaf(xv, w[j], acc[j]);
    }
#pragma unroll
    for (int j = 0; j < 5; ++j) acc[j] += sB[l * 5 + j];

    float m = acc[0];
#pragma unroll
    for (int j = 1; j < 5; ++j) m = fmaxf(m, acc[j]);
#pragma unroll
    for (int off = 1; off < 8; off <<= 1) m = fmaxf(m, __shfl_xor(m, off));
    float s = 0.f;
#pragma unroll
    for (int j = 0; j < 5; ++j) s += expf(acc[j] - m);
#pragma unroll
    for (int off = 1; off < 8; off <<= 1) s += __shfl_xor(s, off);
    float lse = m + logf(s);
    if (row < M) {
#pragma unroll
        for (int j = 0; j < 5; ++j) out[(size_t)row * 40 + l * 5 + j] = acc[j] - lse;
    }
}

// ---------------------------------------------------------------------------
// launch
// ---------------------------------------------------------------------------
extern "C" void kernel_launch(void* const* d_in, const int* in_sizes, int n_in,
                              void* d_out, int out_size, void* d_ws, size_t ws_size,
                              hipStream_t stream) {
    const float* x  = (const float*)d_in[0];
    const int*   ei = (const int*)d_in[1];
    const float* W1 = (const float*)d_in[2];
    const float* b1 = (const float*)d_in[3];
    const float* W2 = (const float*)d_in[4];
    const float* b2 = (const float*)d_in[5];
    const float* Wl = (const float*)d_in[6];
    const float* bl = (const float*)d_in[7];

    const int N = in_sizes[0] / FDIM;   // 50000
    const int E = in_sizes[1] / 2;      // 600000
    const int* src = ei;
    const int* dst = ei + E;

    float* out_lsm = (float*)d_out;                    // [N,40]
    float* x_emb   = (float*)d_out + (size_t)N * ODIM; // [N,128]

    // workspace layout
    char* w = (char*)d_ws;
    int* count  = (int*)w;              // N
    int* rowptr = count + N;            // N+1
    int* cursor = rowptr + N + 1;       // N
    int* csr    = cursor + N;           // E
    float* dinv = (float*)(csr + E);    // N
    size_t small_bytes = (size_t)4 * ((size_t)N + (N + 1) + N + E + N);
    size_t off = (small_bytes + 255) & ~(size_t)255;
    float* bufA = (float*)(w + off);            // N*128 (g)
    float* bufB = bufA + (size_t)N * FDIM;      // N*128 (h)

    hipMemsetAsync(count, 0, (size_t)N * sizeof(int), stream);
    count_edges_k<<<(E + 255) / 256, 256, 0, stream>>>(dst, count, E);
    scan_deg_k<<<1, 1024, 0, stream>>>(count, rowptr, cursor, dinv, N);
    fill_csr_k<<<(E + 255) / 256, 256, 0, stream>>>(src, dst, cursor, csr, E);

    int gblocks = (N + 63) / 64;
    // layer 1
    sgemm128_scale_k<<<gblocks, 256, 0, stream>>>(x, W1, dinv, bufA, N);
    aggregate_k<true><<<N, 128, 0, stream>>>(bufA, dinv, rowptr, csr, b1, bufB, N);
    // layer 2
    sgemm128_scale_k<<<gblocks, 256, 0, stream>>>(bufB, W2, dinv, bufA, N);
    aggregate_k<false><<<N, 128, 0, stream>>>(bufA, dinv, rowptr, csr, b2, x_emb, N);
    // head
    logits_lsm_k<<<(N + 31) / 32, 256, 0, stream>>>(x_emb, Wl, bl, out_lsm, N);
}

// Round 2
// 340.436 us; speedup vs baseline: 1.2829x; 1.2829x over previous
//
#include <hip/hip_runtime.h>
#include <hip/hip_bf16.h>
#include <math.h>

// Problem constants (validated against in_sizes at launch).
#define FDIM 128     // in/hid feature dim
#define ODIM 40      // output classes

// ---------------------------------------------------------------------------
// 1) count in-degrees (dst side) with int atomics
// ---------------------------------------------------------------------------
__global__ void count_edges_k(const int* __restrict__ dst, int* __restrict__ count, int E) {
    int e = blockIdx.x * blockDim.x + threadIdx.x;
    if (e < E) atomicAdd(&count[dst[e]], 1);
}

// ---------------------------------------------------------------------------
// 2a) per-chunk (1024-elem) sums of count; fused dinv = rsqrt(deg+1)
// ---------------------------------------------------------------------------
__global__ __launch_bounds__(256) void block_sum_k(const int* __restrict__ count,
                                                   int* __restrict__ blockSums,
                                                   float* __restrict__ dinv, int n) {
    __shared__ int red[256];
    const int tid = threadIdx.x;
    const int base = blockIdx.x * 1024;
    int s = 0;
#pragma unroll
    for (int j = 0; j < 4; ++j) {
        int i = base + j * 256 + tid;
        if (i < n) {
            int c = count[i];
            s += c;
            dinv[i] = rsqrtf((float)(c + 1));
        }
    }
    red[tid] = s;
    __syncthreads();
    for (int off = 128; off > 0; off >>= 1) {
        if (tid < off) red[tid] += red[tid + off];
        __syncthreads();
    }
    if (tid == 0) blockSums[blockIdx.x] = red[0];
}

// ---------------------------------------------------------------------------
// 2b) one-wave exclusive scan of block sums (nb <= 64); writes rowptr[n]=total
// ---------------------------------------------------------------------------
__global__ __launch_bounds__(64) void scan_sums_k(int* __restrict__ blockSums, int nb,
                                                  int* __restrict__ rowptr, int n) {
    int tid = threadIdx.x;
    int orig = (tid < nb) ? blockSums[tid] : 0;
    int v = orig;
#pragma unroll
    for (int off = 1; off < 64; off <<= 1) {
        int u = __shfl_up(v, off);
        if (tid >= off) v += u;
    }
    // v = inclusive scan
    if (tid < nb) blockSums[tid] = v - orig;      // exclusive offset per chunk
    if (tid == 63) rowptr[n] = v;                 // grand total (lane 63 has full sum)
}

// ---------------------------------------------------------------------------
// 2c) per-chunk local exclusive scan + chunk offset -> rowptr/cursor
// ---------------------------------------------------------------------------
__global__ __launch_bounds__(256) void scan_chunk_k(const int* __restrict__ count,
                                                    const int* __restrict__ blockOffs,
                                                    int* __restrict__ rowptr,
                                                    int* __restrict__ cursor, int n) {
    __shared__ int ts[256];
    const int tid = threadIdx.x;
    const int base = blockIdx.x * 1024 + tid * 4;
    int c[4];
    int s = 0;
#pragma unroll
    for (int j = 0; j < 4; ++j) {
        int i = base + j;
        c[j] = (i < n) ? count[i] : 0;
        s += c[j];
    }
    ts[tid] = s;
    __syncthreads();
    // Hillis-Steele inclusive over 256 thread-sums
    for (int off = 1; off < 256; off <<= 1) {
        int v = (tid >= off) ? ts[tid - off] : 0;
        __syncthreads();
        ts[tid] += v;
        __syncthreads();
    }
    int excl = ts[tid] - s + blockOffs[blockIdx.x];
#pragma unroll
    for (int j = 0; j < 4; ++j) {
        int i = base + j;
        if (i < n) {
            rowptr[i] = excl;
            cursor[i] = excl;
        }
        excl += c[j];
    }
}

// ---------------------------------------------------------------------------
// 3) fill CSR: src ids grouped by dst
// ---------------------------------------------------------------------------
__global__ void fill_csr_k(const int* __restrict__ src, const int* __restrict__ dst,
                           int* __restrict__ cursor, int* __restrict__ csr_src, int E) {
    int e = blockIdx.x * blockDim.x + threadIdx.x;
    if (e < E) {
        int d = dst[e];
        int p = atomicAdd(&cursor[d], 1);
        csr_src[p] = src[e];
    }
}

// ---------------------------------------------------------------------------
// 4) SGEMM: C[M,128] = (A[M,128] @ B[128,128]) * dinv[row]
//    64x128 tile per 256-thread block, BK=16, 4x8 microtile per thread.
// ---------------------------------------------------------------------------
__global__ __launch_bounds__(256) void sgemm128_scale_k(const float* __restrict__ A,
                                                        const float* __restrict__ B,
                                                        const float* __restrict__ dinv,
                                                        float* __restrict__ C, int M) {
    __shared__ float As[16][68];    // transposed A tile: As[k][row], pad to 68
    __shared__ float Bs[16][132];   // Bs[k][n], pad to 132

    const int tid = threadIdx.x;
    const int row0 = blockIdx.x * 64;
    const int ty = tid >> 4;        // 0..15 -> 4 rows each
    const int tx = tid & 15;        // 0..15 -> 8 cols each
    const int arow = tid >> 2;      // 0..63 (A-tile load row)
    const int akq = tid & 3;        // float4 chunk in k-slab

    float acc[4][8];
#pragma unroll
    for (int i = 0; i < 4; ++i)
#pragma unroll
        for (int j = 0; j < 8; ++j) acc[i][j] = 0.f;

    for (int k0 = 0; k0 < 128; k0 += 16) {
        // stage A (64x16) transposed
        float4 av = make_float4(0.f, 0.f, 0.f, 0.f);
        int grow = row0 + arow;
        if (grow < M) av = *(const float4*)&A[(size_t)grow * 128 + k0 + akq * 4];
        As[akq * 4 + 0][arow] = av.x;
        As[akq * 4 + 1][arow] = av.y;
        As[akq * 4 + 2][arow] = av.z;
        As[akq * 4 + 3][arow] = av.w;
        // stage B (16x128): 512 float4s, 2 per thread
#pragma unroll
        for (int t = 0; t < 2; ++t) {
            int f = tid * 2 + t;
            int bk = f >> 5, bn = f & 31;
            float4 bv = *(const float4*)&B[(size_t)(k0 + bk) * 128 + bn * 4];
            *(float4*)&Bs[bk][bn * 4] = bv;
        }
        __syncthreads();
#pragma unroll
        for (int k = 0; k < 16; ++k) {
            float4 a4 = *(float4*)&As[k][ty * 4];
            float4 b0 = *(float4*)&Bs[k][tx * 8];
            float4 b1 = *(float4*)&Bs[k][tx * 8 + 4];
            float a[4] = {a4.x, a4.y, a4.z, a4.w};
            float b[8] = {b0.x, b0.y, b0.z, b0.w, b1.x, b1.y, b1.z, b1.w};
#pragma unroll
            for (int i = 0; i < 4; ++i)
#pragma unroll
                for (int j = 0; j < 8; ++j) acc[i][j] = fmaf(a[i], b[j], acc[i][j]);
        }
        __syncthreads();
    }
#pragma unroll
    for (int i = 0; i < 4; ++i) {
        int row = row0 + ty * 4 + i;
        if (row < M) {
            float sc = dinv[row];
            float4 o0 = make_float4(acc[i][0] * sc, acc[i][1] * sc, acc[i][2] * sc, acc[i][3] * sc);
            float4 o1 = make_float4(acc[i][4] * sc, acc[i][5] * sc, acc[i][6] * sc, acc[i][7] * sc);
            *(float4*)&C[(size_t)row * 128 + tx * 8] = o0;
            *(float4*)&C[(size_t)row * 128 + tx * 8 + 4] = o1;
        }
    }
}

// ---------------------------------------------------------------------------
// 5) aggregate: out[d,c] = act( dinv[d]*(g[d,c] + sum_{s in N(d)} g[s,c]) + b[c] )
//    one block (128 threads) per dst node; coalesced row gathers.
// ---------------------------------------------------------------------------
template <bool RELU>
__global__ __launch_bounds__(128) void aggregate_k(const float* __restrict__ g,
                                                   const float* __restrict__ dinv,
                                                   const int* __restrict__ rowptr,
                                                   const int* __restrict__ csr_src,
                                                   const float* __restrict__ bias,
                                                   float* __restrict__ out, int n) {
    int d = blockIdx.x;
    int c = threadIdx.x;
    float acc = g[(size_t)d * 128 + c];  // self-loop term
    int e = rowptr[d], end = rowptr[d + 1];
    for (; e + 1 < end; e += 2) {
        int s0 = csr_src[e];
        int s1 = csr_src[e + 1];
        float v0 = g[(size_t)s0 * 128 + c];
        float v1 = g[(size_t)s1 * 128 + c];
        acc += v0 + v1;
    }
    if (e < end) {
        int s0 = csr_src[e];
        acc += g[(size_t)s0 * 128 + c];
    }
    float v = fmaf(dinv[d], acc, bias[c]);
    if (RELU) v = fmaxf(v, 0.f);
    out[(size_t)d * 128 + c] = v;
}

// ---------------------------------------------------------------------------
// 6) logits = x_emb @ Wl + bl; log_softmax over 40 cols.
//    32 rows per 256-thread block; 8 lanes per row, 5 cols per lane.
// ---------------------------------------------------------------------------
__global__ __launch_bounds__(256) void logits_lsm_k(const float* __restrict__ xe,
                                                    const float* __restrict__ Wl,
                                                    const float* __restrict__ bl,
                                                    float* __restrict__ out, int M) {
    __shared__ float sW[128 * 40];
    __shared__ float sX[32][132];
    __shared__ float sB[40];
    const int tid = threadIdx.x;
    const int row0 = blockIdx.x * 32;

    for (int i = tid; i < (128 * 40) / 4; i += 256)
        ((float4*)sW)[i] = ((const float4*)Wl)[i];
    if (tid < 40) sB[tid] = bl[tid];
    for (int i = tid; i < 32 * 32; i += 256) {  // 1024 float4s
        int r = i >> 5, cq = i & 31;
        float4 v = make_float4(0.f, 0.f, 0.f, 0.f);
        if (row0 + r < M) v = *(const float4*)&xe[(size_t)(row0 + r) * 128 + cq * 4];
        *(float4*)&sX[r][cq * 4] = v;
    }
    __syncthreads();

    const int g = tid >> 3;  // local row 0..31
    const int l = tid & 7;   // lane-in-row
    const int row = row0 + g;
    float acc[5] = {0.f, 0.f, 0.f, 0.f, 0.f};
    for (int k = 0; k < 128; ++k) {
        float xv = sX[g][k];
        const float* w = &sW[k * 40 + l * 5];
#pragma unroll
        for (int j = 0; j < 5; ++j) acc[j] = fmaf(xv, w[j], acc[j]);
    }
#pragma unroll
    for (int j = 0; j < 5; ++j) acc[j] += sB[l * 5 + j];

    float m = acc[0];
#pragma unroll
    for (int j = 1; j < 5; ++j) m = fmaxf(m, acc[j]);
#pragma unroll
    for (int off = 1; off < 8; off <<= 1) m = fmaxf(m, __shfl_xor(m, off));
    float s = 0.f;
#pragma unroll
    for (int j = 0; j < 5; ++j) s += expf(acc[j] - m);
#pragma unroll
    for (int off = 1; off < 8; off <<= 1) s += __shfl_xor(s, off);
    float lse = m + logf(s);
    if (row < M) {
#pragma unroll
        for (int j = 0; j < 5; ++j) out[(size_t)row * 40 + l * 5 + j] = acc[j] - lse;
    }
}

// ---------------------------------------------------------------------------
// launch
// ---------------------------------------------------------------------------
extern "C" void kernel_launch(void* const* d_in, const int* in_sizes, int n_in,
                              void* d_out, int out_size, void* d_ws, size_t ws_size,
                              hipStream_t stream) {
    const float* x  = (const float*)d_in[0];
    const int*   ei = (const int*)d_in[1];
    const float* W1 = (const float*)d_in[2];
    const float* b1 = (const float*)d_in[3];
    const float* W2 = (const float*)d_in[4];
    const float* b2 = (const float*)d_in[5];
    const float* Wl = (const float*)d_in[6];
    const float* bl = (const float*)d_in[7];

    const int N = in_sizes[0] / FDIM;   // 50000
    const int E = in_sizes[1] / 2;      // 600000
    const int* src = ei;
    const int* dst = ei + E;

    float* out_lsm = (float*)d_out;                    // [N,40]
    float* x_emb   = (float*)d_out + (size_t)N * ODIM; // [N,128]

    // workspace layout
    char* w = (char*)d_ws;
    int* count  = (int*)w;              // N
    int* rowptr = count + N;            // N+1
    int* cursor = rowptr + N + 1;       // N
    int* csr    = cursor + N;           // E
    float* dinv = (float*)(csr + E);    // N
    int* blockSums = (int*)(dinv + N);  // <=64
    size_t small_bytes = (size_t)4 * ((size_t)N + (N + 1) + N + E + N + 64);
    size_t off = (small_bytes + 255) & ~(size_t)255;
    float* bufA = (float*)(w + off);            // N*128 (g)
    float* bufB = bufA + (size_t)N * FDIM;      // N*128 (h)

    const int nchunk = (N + 1023) / 1024;       // 49 for N=50000 (<=64 required)

    hipMemsetAsync(count, 0, (size_t)N * sizeof(int), stream);
    count_edges_k<<<(E + 255) / 256, 256, 0, stream>>>(dst, count, E);
    block_sum_k<<<nchunk, 256, 0, stream>>>(count, blockSums, dinv, N);
    scan_sums_k<<<1, 64, 0, stream>>>(blockSums, nchunk, rowptr, N);
    scan_chunk_k<<<nchunk, 256, 0, stream>>>(count, blockSums, rowptr, cursor, N);
    fill_csr_k<<<(E + 255) / 256, 256, 0, stream>>>(src, dst, cursor, csr, E);

    int gblocks = (N + 63) / 64;
    // layer 1
    sgemm128_scale_k<<<gblocks, 256, 0, stream>>>(x, W1, dinv, bufA, N);
    aggregate_k<true><<<N, 128, 0, stream>>>(bufA, dinv, rowptr, csr, b1, bufB, N);
    // layer 2
    sgemm128_scale_k<<<gblocks, 256, 0, stream>>>(bufB, W2, dinv, bufA, N);
    aggregate_k<false><<<N, 128, 0, stream>>>(bufA, dinv, rowptr, csr, b2, x_emb, N);
    // head
    logits_lsm_k<<<(N + 31) / 32, 256, 0, stream>>>(x_emb, Wl, bl, out_lsm, N);
}

// Round 3
// 303.494 us; speedup vs baseline: 1.4390x; 1.1217x over previous
//
#include <hip/hip_runtime.h>
#include <hip/hip_bf16.h>
#include <math.h>
#include <type_traits>

// Problem constants (validated against in_sizes at launch).
#define FDIM 128     // in/hid feature dim
#define ODIM 40      // output classes

// ---- bf16 pack/unpack helpers (manual, RNE) --------------------------------
__device__ __forceinline__ float bf_lo(unsigned v) { return __uint_as_float(v << 16); }
__device__ __forceinline__ float bf_hi(unsigned v) { return __uint_as_float(v & 0xFFFF0000u); }
__device__ __forceinline__ unsigned f2bf(float f) {   // round-to-nearest-even
    unsigned u = __float_as_uint(f);
    return (u + 0x7FFFu + ((u >> 16) & 1u)) >> 16;
}

// ---------------------------------------------------------------------------
// 1) count in-degrees (dst side) with int atomics
// ---------------------------------------------------------------------------
__global__ void count_edges_k(const int* __restrict__ dst, int* __restrict__ count, int E) {
    int e = blockIdx.x * blockDim.x + threadIdx.x;
    if (e < E) atomicAdd(&count[dst[e]], 1);
}

// ---------------------------------------------------------------------------
// 2a) per-chunk (1024-elem) sums of count; fused dinv = rsqrt(deg+1)
// ---------------------------------------------------------------------------
__global__ __launch_bounds__(256) void block_sum_k(const int* __restrict__ count,
                                                   int* __restrict__ blockSums,
                                                   float* __restrict__ dinv, int n) {
    __shared__ int red[256];
    const int tid = threadIdx.x;
    const int base = blockIdx.x * 1024;
    int s = 0;
#pragma unroll
    for (int j = 0; j < 4; ++j) {
        int i = base + j * 256 + tid;
        if (i < n) {
            int c = count[i];
            s += c;
            dinv[i] = rsqrtf((float)(c + 1));
        }
    }
    red[tid] = s;
    __syncthreads();
    for (int off = 128; off > 0; off >>= 1) {
        if (tid < off) red[tid] += red[tid + off];
        __syncthreads();
    }
    if (tid == 0) blockSums[blockIdx.x] = red[0];
}

// ---------------------------------------------------------------------------
// 2b) one-wave exclusive scan of block sums (nb <= 64); writes rowptr[n]=total
// ---------------------------------------------------------------------------
__global__ __launch_bounds__(64) void scan_sums_k(int* __restrict__ blockSums, int nb,
                                                  int* __restrict__ rowptr, int n) {
    int tid = threadIdx.x;
    int orig = (tid < nb) ? blockSums[tid] : 0;
    int v = orig;
#pragma unroll
    for (int off = 1; off < 64; off <<= 1) {
        int u = __shfl_up(v, off);
        if (tid >= off) v += u;
    }
    if (tid < nb) blockSums[tid] = v - orig;      // exclusive offset per chunk
    if (tid == 63) rowptr[n] = v;                 // grand total
}

// ---------------------------------------------------------------------------
// 2c) per-chunk local exclusive scan + chunk offset -> rowptr/cursor
// ---------------------------------------------------------------------------
__global__ __launch_bounds__(256) void scan_chunk_k(const int* __restrict__ count,
                                                    const int* __restrict__ blockOffs,
                                                    int* __restrict__ rowptr,
                                                    int* __restrict__ cursor, int n) {
    __shared__ int ts[256];
    const int tid = threadIdx.x;
    const int base = blockIdx.x * 1024 + tid * 4;
    int c[4];
    int s = 0;
#pragma unroll
    for (int j = 0; j < 4; ++j) {
        int i = base + j;
        c[j] = (i < n) ? count[i] : 0;
        s += c[j];
    }
    ts[tid] = s;
    __syncthreads();
    for (int off = 1; off < 256; off <<= 1) {
        int v = (tid >= off) ? ts[tid - off] : 0;
        __syncthreads();
        ts[tid] += v;
        __syncthreads();
    }
    int excl = ts[tid] - s + blockOffs[blockIdx.x];
#pragma unroll
    for (int j = 0; j < 4; ++j) {
        int i = base + j;
        if (i < n) {
            rowptr[i] = excl;
            cursor[i] = excl;
        }
        excl += c[j];
    }
}

// ---------------------------------------------------------------------------
// 3) fill CSR: src ids grouped by dst
// ---------------------------------------------------------------------------
__global__ void fill_csr_k(const int* __restrict__ src, const int* __restrict__ dst,
                           int* __restrict__ cursor, int* __restrict__ csr_src, int E) {
    int e = blockIdx.x * blockDim.x + threadIdx.x;
    if (e < E) {
        int d = dst[e];
        int p = atomicAdd(&cursor[d], 1);
        csr_src[p] = src[e];
    }
}

// ---------------------------------------------------------------------------
// 4) SGEMM: Cb[M,128](bf16) = (A[M,128] @ B[128,128]) * dinv[row]
//    64x128 tile per 256-thread block, BK=16, 4x8 microtile per thread.
//    A is fp32 (layer 1) or bf16-as-ushort (layer 2). C packed 2xbf16/uint.
// ---------------------------------------------------------------------------
template <typename AT>
__global__ __launch_bounds__(256) void sgemm128_scale_k(const AT* __restrict__ A,
                                                        const float* __restrict__ B,
                                                        const float* __restrict__ dinv,
                                                        unsigned* __restrict__ Cb, int M) {
    __shared__ float As[16][68];    // transposed A tile: As[k][row]
    __shared__ float Bs[16][132];   // Bs[k][n]

    const int tid = threadIdx.x;
    const int row0 = blockIdx.x * 64;
    const int ty = tid >> 4;        // 0..15 -> 4 rows each
    const int tx = tid & 15;        // 0..15 -> 8 cols each
    const int arow = tid >> 2;      // 0..63 (A-tile load row)
    const int akq = tid & 3;        // 4-channel chunk in k-slab

    float acc[4][8];
#pragma unroll
    for (int i = 0; i < 4; ++i)
#pragma unroll
        for (int j = 0; j < 8; ++j) acc[i][j] = 0.f;

    for (int k0 = 0; k0 < 128; k0 += 16) {
        float4 av = make_float4(0.f, 0.f, 0.f, 0.f);
        int grow = row0 + arow;
        if (grow < M) {
            if constexpr (std::is_same_v<AT, float>) {
                av = *(const float4*)&A[(size_t)grow * 128 + k0 + akq * 4];
            } else {
                uint2 uv = *(const uint2*)&A[(size_t)grow * 128 + k0 + akq * 4];
                av = make_float4(bf_lo(uv.x), bf_hi(uv.x), bf_lo(uv.y), bf_hi(uv.y));
            }
        }
        As[akq * 4 + 0][arow] = av.x;
        As[akq * 4 + 1][arow] = av.y;
        As[akq * 4 + 2][arow] = av.z;
        As[akq * 4 + 3][arow] = av.w;
#pragma unroll
        for (int t = 0; t < 2; ++t) {
            int f = tid * 2 + t;
            int bk = f >> 5, bn = f & 31;
            float4 bv = *(const float4*)&B[(size_t)(k0 + bk) * 128 + bn * 4];
            *(float4*)&Bs[bk][bn * 4] = bv;
        }
        __syncthreads();
#pragma unroll
        for (int k = 0; k < 16; ++k) {
            float4 a4 = *(float4*)&As[k][ty * 4];
            float4 b0 = *(float4*)&Bs[k][tx * 8];
            float4 b1 = *(float4*)&Bs[k][tx * 8 + 4];
            float a[4] = {a4.x, a4.y, a4.z, a4.w};
            float b[8] = {b0.x, b0.y, b0.z, b0.w, b1.x, b1.y, b1.z, b1.w};
#pragma unroll
            for (int i = 0; i < 4; ++i)
#pragma unroll
                for (int j = 0; j < 8; ++j) acc[i][j] = fmaf(a[i], b[j], acc[i][j]);
        }
        __syncthreads();
    }
#pragma unroll
    for (int i = 0; i < 4; ++i) {
        int row = row0 + ty * 4 + i;
        if (row < M) {
            float sc = dinv[row];
            uint4 o;
            o.x = f2bf(acc[i][0] * sc) | (f2bf(acc[i][1] * sc) << 16);
            o.y = f2bf(acc[i][2] * sc) | (f2bf(acc[i][3] * sc) << 16);
            o.z = f2bf(acc[i][4] * sc) | (f2bf(acc[i][5] * sc) << 16);
            o.w = f2bf(acc[i][6] * sc) | (f2bf(acc[i][7] * sc) << 16);
            *(uint4*)&Cb[(size_t)row * 64 + tx * 4] = o;
        }
    }
}

// ---------------------------------------------------------------------------
// 5) aggregate: out[d,:] = act( dinv[d]*(g[d,:] + sum_{s in N(d)} g[s,:]) + b )
//    one 64-lane wave per dst node; each lane owns 2 channels (packed bf16x2).
//    Row read = 64 lanes x 4 B = 256 B coalesced. fp32 accumulation.
// ---------------------------------------------------------------------------
template <bool RELU, bool OUT_BF16>
__global__ __launch_bounds__(64) void aggregate_k(const unsigned* __restrict__ g,
                                                  const float* __restrict__ dinv,
                                                  const int* __restrict__ rowptr,
                                                  const int* __restrict__ csr_src,
                                                  const float* __restrict__ bias,
                                                  void* __restrict__ outv, int n) {
    const int d = blockIdx.x;
    const int c = threadIdx.x;            // lane: channels 2c, 2c+1
    unsigned self = g[(size_t)d * 64 + c];
    float ax = bf_lo(self), ay = bf_hi(self);
    int e = rowptr[d], end = rowptr[d + 1];
    for (; e + 3 < end; e += 4) {
        int s0 = csr_src[e], s1 = csr_src[e + 1], s2 = csr_src[e + 2], s3 = csr_src[e + 3];
        unsigned v0 = g[(size_t)s0 * 64 + c];
        unsigned v1 = g[(size_t)s1 * 64 + c];
        unsigned v2 = g[(size_t)s2 * 64 + c];
        unsigned v3 = g[(size_t)s3 * 64 + c];
        ax += (bf_lo(v0) + bf_lo(v1)) + (bf_lo(v2) + bf_lo(v3));
        ay += (bf_hi(v0) + bf_hi(v1)) + (bf_hi(v2) + bf_hi(v3));
    }
    for (; e < end; ++e) {
        unsigned v = g[(size_t)csr_src[e] * 64 + c];
        ax += bf_lo(v);
        ay += bf_hi(v);
    }
    float sc = dinv[d];
    float ox = fmaf(sc, ax, bias[2 * c]);
    float oy = fmaf(sc, ay, bias[2 * c + 1]);
    if (RELU) { ox = fmaxf(ox, 0.f); oy = fmaxf(oy, 0.f); }
    if constexpr (OUT_BF16) {
        ((unsigned*)outv)[(size_t)d * 64 + c] = f2bf(ox) | (f2bf(oy) << 16);
    } else {
        ((float2*)outv)[(size_t)d * 64 + c] = make_float2(ox, oy);
    }
}

// ---------------------------------------------------------------------------
// 6) logits = x_emb @ Wl + bl; log_softmax over 40 cols.
// ---------------------------------------------------------------------------
__global__ __launch_bounds__(256) void logits_lsm_k(const float* __restrict__ xe,
                                                    const float* __restrict__ Wl,
                                                    const float* __restrict__ bl,
                                                    float* __restrict__ out, int M) {
    __shared__ float sW[128 * 40];
    __shared__ float sX[32][132];
    __shared__ float sB[40];
    const int tid = threadIdx.x;
    const int row0 = blockIdx.x * 32;

    for (int i = tid; i < (128 * 40) / 4; i += 256)
        ((float4*)sW)[i] = ((const float4*)Wl)[i];
    if (tid < 40) sB[tid] = bl[tid];
    for (int i = tid; i < 32 * 32; i += 256) {
        int r = i >> 5, cq = i & 31;
        float4 v = make_float4(0.f, 0.f, 0.f, 0.f);
        if (row0 + r < M) v = *(const float4*)&xe[(size_t)(row0 + r) * 128 + cq * 4];
        *(float4*)&sX[r][cq * 4] = v;
    }
    __syncthreads();

    const int g = tid >> 3;  // local row 0..31
    const int l = tid & 7;   // lane-in-row
    const int row = row0 + g;
    float acc[5] = {0.f, 0.f, 0.f, 0.f, 0.f};
    for (int k = 0; k < 128; ++k) {
        float xv = sX[g][k];
        const float* w = &sW[k * 40 + l * 5];
#pragma unroll
        for (int j = 0; j < 5; ++j) acc[j] = fmaf(xv, w[j], acc[j]);
    }
#pragma unroll
    for (int j = 0; j < 5; ++j) acc[j] += sB[l * 5 + j];

    float m = acc[0];
#pragma unroll
    for (int j = 1; j < 5; ++j) m = fmaxf(m, acc[j]);
#pragma unroll
    for (int off = 1; off < 8; off <<= 1) m = fmaxf(m, __shfl_xor(m, off));
    float s = 0.f;
#pragma unroll
    for (int j = 0; j < 5; ++j) s += expf(acc[j] - m);
#pragma unroll
    for (int off = 1; off < 8; off <<= 1) s += __shfl_xor(s, off);
    float lse = m + logf(s);
    if (row < M) {
#pragma unroll
        for (int j = 0; j < 5; ++j) out[(size_t)row * 40 + l * 5 + j] = acc[j] - lse;
    }
}

// ---------------------------------------------------------------------------
// launch
// ---------------------------------------------------------------------------
extern "C" void kernel_launch(void* const* d_in, const int* in_sizes, int n_in,
                              void* d_out, int out_size, void* d_ws, size_t ws_size,
                              hipStream_t stream) {
    const float* x  = (const float*)d_in[0];
    const int*   ei = (const int*)d_in[1];
    const float* W1 = (const float*)d_in[2];
    const float* b1 = (const float*)d_in[3];
    const float* W2 = (const float*)d_in[4];
    const float* b2 = (const float*)d_in[5];
    const float* Wl = (const float*)d_in[6];
    const float* bl = (const float*)d_in[7];

    const int N = in_sizes[0] / FDIM;   // 50000
    const int E = in_sizes[1] / 2;      // 600000
    const int* src = ei;
    const int* dst = ei + E;

    float* out_lsm = (float*)d_out;                    // [N,40]
    float* x_emb   = (float*)d_out + (size_t)N * ODIM; // [N,128]

    // workspace layout
    char* w = (char*)d_ws;
    int* count  = (int*)w;              // N
    int* rowptr = count + N;            // N+1
    int* cursor = rowptr + N + 1;       // N
    int* csr    = cursor + N;           // E
    float* dinv = (float*)(csr + E);    // N
    int* blockSums = (int*)(dinv + N);  // <=64
    size_t small_bytes = (size_t)4 * ((size_t)N + (N + 1) + N + E + N + 64);
    size_t off = (small_bytes + 255) & ~(size_t)255;
    unsigned* bufA = (unsigned*)(w + off);       // N*64 uints (g, bf16x2)
    unsigned* bufB = bufA + (size_t)N * 64;      // N*64 uints (h, bf16x2)

    const int nchunk = (N + 1023) / 1024;        // 49 for N=50000 (<=64 required)

    hipMemsetAsync(count, 0, (size_t)N * sizeof(int), stream);
    count_edges_k<<<(E + 255) / 256, 256, 0, stream>>>(dst, count, E);
    block_sum_k<<<nchunk, 256, 0, stream>>>(count, blockSums, dinv, N);
    scan_sums_k<<<1, 64, 0, stream>>>(blockSums, nchunk, rowptr, N);
    scan_chunk_k<<<nchunk, 256, 0, stream>>>(count, blockSums, rowptr, cursor, N);
    fill_csr_k<<<(E + 255) / 256, 256, 0, stream>>>(src, dst, cursor, csr, E);

    int gblocks = (N + 63) / 64;
    // layer 1
    sgemm128_scale_k<float><<<gblocks, 256, 0, stream>>>(x, W1, dinv, bufA, N);
    aggregate_k<true, true><<<N, 64, 0, stream>>>(bufA, dinv, rowptr, csr, b1, bufB, N);
    // layer 2
    sgemm128_scale_k<unsigned short><<<gblocks, 256, 0, stream>>>(
        (const unsigned short*)bufB, W2, dinv, bufA, N);
    aggregate_k<false, false><<<N, 64, 0, stream>>>(bufA, dinv, rowptr, csr, b2, x_emb, N);
    // head
    logits_lsm_k<<<(N + 31) / 32, 256, 0, stream>>>(x_emb, Wl, bl, out_lsm, N);
}

// Round 5
// 266.381 us; speedup vs baseline: 1.6395x; 1.1393x over previous
//
#include <hip/hip_runtime.h>
#include <hip/hip_bf16.h>
#include <math.h>
#include <type_traits>

#define FDIM 128     // in/hid feature dim
#define ODIM 40      // output classes

typedef __attribute__((ext_vector_type(8))) short bf16x8;
typedef __attribute__((ext_vector_type(4))) float f32x4;

// ---- bf16 pack/unpack helpers (manual, RNE) --------------------------------
__device__ __forceinline__ float bf_lo(unsigned v) { return __uint_as_float(v << 16); }
__device__ __forceinline__ float bf_hi(unsigned v) { return __uint_as_float(v & 0xFFFF0000u); }
__device__ __forceinline__ unsigned f2bf(float f) {   // round-to-nearest-even
    unsigned u = __float_as_uint(f);
    return (u + 0x7FFFu + ((u >> 16) & 1u)) >> 16;
}

// ---------------------------------------------------------------------------
// 1) count in-degrees (dst side) with int atomics
// ---------------------------------------------------------------------------
__global__ void count_edges_k(const int* __restrict__ dst, int* __restrict__ count, int E) {
    int e = blockIdx.x * blockDim.x + threadIdx.x;
    if (e < E) atomicAdd(&count[dst[e]], 1);
}

// ---------------------------------------------------------------------------
// 2a) per-chunk (1024-elem) sums of count; fused dinv = rsqrt(deg+1)
// ---------------------------------------------------------------------------
__global__ __launch_bounds__(256) void block_sum_k(const int* __restrict__ count,
                                                   int* __restrict__ blockSums,
                                                   float* __restrict__ dinv, int n) {
    __shared__ int red[256];
    const int tid = threadIdx.x;
    const int base = blockIdx.x * 1024;
    int s = 0;
#pragma unroll
    for (int j = 0; j < 4; ++j) {
        int i = base + j * 256 + tid;
        if (i < n) {
            int c = count[i];
            s += c;
            dinv[i] = rsqrtf((float)(c + 1));
        }
    }
    red[tid] = s;
    __syncthreads();
    for (int off = 128; off > 0; off >>= 1) {
        if (tid < off) red[tid] += red[tid + off];
        __syncthreads();
    }
    if (tid == 0) blockSums[blockIdx.x] = red[0];
}

// ---------------------------------------------------------------------------
// 2b) one-wave exclusive scan of block sums (nb <= 64); writes rowptr[n]=total
// ---------------------------------------------------------------------------
__global__ __launch_bounds__(64) void scan_sums_k(int* __restrict__ blockSums, int nb,
                                                  int* __restrict__ rowptr, int n) {
    int tid = threadIdx.x;
    int orig = (tid < nb) ? blockSums[tid] : 0;
    int v = orig;
#pragma unroll
    for (int off = 1; off < 64; off <<= 1) {
        int u = __shfl_up(v, off);
        if (tid >= off) v += u;
    }
    if (tid < nb) blockSums[tid] = v - orig;      // exclusive offset per chunk
    if (tid == 63) rowptr[n] = v;                 // grand total
}

// ---------------------------------------------------------------------------
// 2c) per-chunk local exclusive scan + chunk offset -> rowptr/cursor
// ---------------------------------------------------------------------------
__global__ __launch_bounds__(256) void scan_chunk_k(const int* __restrict__ count,
                                                    const int* __restrict__ blockOffs,
                                                    int* __restrict__ rowptr,
                                                    int* __restrict__ cursor, int n) {
    __shared__ int ts[256];
    const int tid = threadIdx.x;
    const int base = blockIdx.x * 1024 + tid * 4;
    int c[4];
    int s = 0;
#pragma unroll
    for (int j = 0; j < 4; ++j) {
        int i = base + j;
        c[j] = (i < n) ? count[i] : 0;
        s += c[j];
    }
    ts[tid] = s;
    __syncthreads();
    for (int off = 1; off < 256; off <<= 1) {
        int v = (tid >= off) ? ts[tid - off] : 0;
        __syncthreads();
        ts[tid] += v;
        __syncthreads();
    }
    int excl = ts[tid] - s + blockOffs[blockIdx.x];
#pragma unroll
    for (int j = 0; j < 4; ++j) {
        int i = base + j;
        if (i < n) {
            rowptr[i] = excl;
            cursor[i] = excl;
        }
        excl += c[j];
    }
}

// ---------------------------------------------------------------------------
// 3) fill CSR: src ids grouped by dst
// ---------------------------------------------------------------------------
__global__ void fill_csr_k(const int* __restrict__ src, const int* __restrict__ dst,
                           int* __restrict__ cursor, int* __restrict__ csr_src, int E) {
    int e = blockIdx.x * blockDim.x + threadIdx.x;
    if (e < E) {
        int d = dst[e];
        int p = atomicAdd(&cursor[d], 1);
        csr_src[p] = src[e];
    }
}

// ---------------------------------------------------------------------------
// 3b) convert W[128][128] fp32 -> Wt[n][k] bf16 (transposed for B-fragments)
// ---------------------------------------------------------------------------
__global__ __launch_bounds__(256) void convert_wt_k(const float* __restrict__ W,
                                                    unsigned short* __restrict__ Wt) {
    int idx = blockIdx.x * 256 + threadIdx.x;   // 16384
    int k = idx >> 7, n = idx & 127;
    Wt[n * 128 + k] = (unsigned short)f2bf(W[k * 128 + n]);
}

// ---------------------------------------------------------------------------
// 4) MFMA GEMM: Cb[M,128](bf16) = (A[M,128] @ W) * dinv[row]
//    Wt is W transposed, bf16 [n][k]. 64-row tile per 256-thread block.
//    Whole K=128 staged to LDS once; 4 waves x 32 cols; 16x16x32 bf16 MFMA.
//    A fp32 (layer 1) or bf16-as-ushort (layer 2).
//    Staging trip counts: A-fp32 64*32 float4 = 2048 -> 8 iters of 256 thr;
//    A-bf16 64*16 uint4 = 1024 -> 4 iters; B 128*16 uint4 = 2048 -> 8 iters.
//    (R4 bug: A-bf16 ran 8 iters and B ran 16 -> OOB LDS clobber of Bs.)
// ---------------------------------------------------------------------------
template <typename AT>
__global__ __launch_bounds__(256) void mfma_gemm_k(const AT* __restrict__ A,
                                                   const unsigned short* __restrict__ Wt,
                                                   const float* __restrict__ dinv,
                                                   unsigned short* __restrict__ Cb, int M) {
    __shared__ unsigned short As[64][136];   // row stride 272 B = 4 banks mod 32
    __shared__ unsigned short Bs[128][136];

    const int tid = threadIdx.x;
    const int row0 = blockIdx.x * 64;

    // ---- stage A (64 x 128) ----
    if constexpr (std::is_same_v<AT, float>) {
#pragma unroll
        for (int i = 0; i < 8; ++i) {        // 64 rows * 32 float4 = 2048
            int fidx = i * 256 + tid;
            int r = fidx >> 5, kq = fidx & 31;
            float4 v = make_float4(0.f, 0.f, 0.f, 0.f);
            int grow = row0 + r;
            if (grow < M) v = *(const float4*)&A[(size_t)grow * 128 + kq * 4];
            unsigned lo = f2bf(v.x) | (f2bf(v.y) << 16);
            unsigned hi = f2bf(v.z) | (f2bf(v.w) << 16);
            *(uint2*)&As[r][kq * 4] = make_uint2(lo, hi);
        }
    } else {
#pragma unroll
        for (int i = 0; i < 4; ++i) {        // 64 rows * 16 uint4 = 1024
            int fidx = i * 256 + tid;
            int r = fidx >> 4, kq = fidx & 15;
            uint4 v = make_uint4(0, 0, 0, 0);
            int grow = row0 + r;
            if (grow < M) v = *(const uint4*)&A[(size_t)grow * 128 + kq * 8];
            *(uint4*)&As[r][kq * 8] = v;
        }
    }
    // ---- stage B (128 x 128) ----
#pragma unroll
    for (int i = 0; i < 8; ++i) {            // 128 rows * 16 uint4 = 2048
        int fidx = i * 256 + tid;
        int r = fidx >> 4, kq = fidx & 15;
        *(uint4*)&Bs[r][kq * 8] = *(const uint4*)&Wt[(size_t)r * 128 + kq * 8];
    }
    __syncthreads();

    // ---- compute ----
    const int lane = tid & 63;
    const int wv = tid >> 6;       // wave 0..3 -> cols wv*32 .. +31
    const int n0 = wv * 32;
    const int mrow = lane & 15;
    const int quad = lane >> 4;

    f32x4 acc[4][2];
#pragma unroll
    for (int mt = 0; mt < 4; ++mt)
#pragma unroll
        for (int nt = 0; nt < 2; ++nt) acc[mt][nt] = (f32x4){0.f, 0.f, 0.f, 0.f};

#pragma unroll
    for (int kk = 0; kk < 128; kk += 32) {
        int ko = kk + quad * 8;
        bf16x8 af[4], bf[2];
#pragma unroll
        for (int mt = 0; mt < 4; ++mt) af[mt] = *(const bf16x8*)&As[mt * 16 + mrow][ko];
#pragma unroll
        for (int nt = 0; nt < 2; ++nt) bf[nt] = *(const bf16x8*)&Bs[n0 + nt * 16 + mrow][ko];
#pragma unroll
        for (int mt = 0; mt < 4; ++mt)
#pragma unroll
            for (int nt = 0; nt < 2; ++nt)
                acc[mt][nt] = __builtin_amdgcn_mfma_f32_16x16x32_bf16(af[mt], bf[nt], acc[mt][nt], 0, 0, 0);
    }

    // ---- epilogue: C layout col=lane&15, row=quad*4+reg ----
#pragma unroll
    for (int mt = 0; mt < 4; ++mt) {
#pragma unroll
        for (int reg = 0; reg < 4; ++reg) {
            int grow = row0 + mt * 16 + quad * 4 + reg;
            if (grow < M) {
                float sc = dinv[grow];
#pragma unroll
                for (int nt = 0; nt < 2; ++nt) {
                    int col = n0 + nt * 16 + mrow;
                    Cb[(size_t)grow * 128 + col] = (unsigned short)f2bf(acc[mt][nt][reg] * sc);
                }
            }
        }
    }
}

// ---------------------------------------------------------------------------
// 5) aggregate: out[d,:] = act( dinv[d]*(g[d,:] + sum_{s in N(d)} g[s,:]) + b )
//    one 64-lane wave per dst node; each lane owns 2 channels (packed bf16x2).
// ---------------------------------------------------------------------------
template <bool RELU, bool OUT_BF16>
__global__ __launch_bounds__(64) void aggregate_k(const unsigned* __restrict__ g,
                                                  const float* __restrict__ dinv,
                                                  const int* __restrict__ rowptr,
                                                  const int* __restrict__ csr_src,
                                                  const float* __restrict__ bias,
                                                  void* __restrict__ outv, int n) {
    const int d = blockIdx.x;
    const int c = threadIdx.x;            // lane: channels 2c, 2c+1
    unsigned self = g[(size_t)d * 64 + c];
    float ax = bf_lo(self), ay = bf_hi(self);
    int e = rowptr[d], end = rowptr[d + 1];
    for (; e + 3 < end; e += 4) {
        int s0 = csr_src[e], s1 = csr_src[e + 1], s2 = csr_src[e + 2], s3 = csr_src[e + 3];
        unsigned v0 = g[(size_t)s0 * 64 + c];
        unsigned v1 = g[(size_t)s1 * 64 + c];
        unsigned v2 = g[(size_t)s2 * 64 + c];
        unsigned v3 = g[(size_t)s3 * 64 + c];
        ax += (bf_lo(v0) + bf_lo(v1)) + (bf_lo(v2) + bf_lo(v3));
        ay += (bf_hi(v0) + bf_hi(v1)) + (bf_hi(v2) + bf_hi(v3));
    }
    for (; e < end; ++e) {
        unsigned v = g[(size_t)csr_src[e] * 64 + c];
        ax += bf_lo(v);
        ay += bf_hi(v);
    }
    float sc = dinv[d];
    float ox = fmaf(sc, ax, bias[2 * c]);
    float oy = fmaf(sc, ay, bias[2 * c + 1]);
    if (RELU) { ox = fmaxf(ox, 0.f); oy = fmaxf(oy, 0.f); }
    if constexpr (OUT_BF16) {
        ((unsigned*)outv)[(size_t)d * 64 + c] = f2bf(ox) | (f2bf(oy) << 16);
    } else {
        ((float2*)outv)[(size_t)d * 64 + c] = make_float2(ox, oy);
    }
}

// ---------------------------------------------------------------------------
// 6) logits = x_emb @ Wl + bl; log_softmax over 40 cols.
// ---------------------------------------------------------------------------
__global__ __launch_bounds__(256) void logits_lsm_k(const float* __restrict__ xe,
                                                    const float* __restrict__ Wl,
                                                    const float* __restrict__ bl,
                                                    float* __restrict__ out, int M) {
    __shared__ float sW[128 * 40];
    __shared__ float sX[32][132];
    __shared__ float sB[40];
    const int tid = threadIdx.x;
    const int row0 = blockIdx.x * 32;

    for (int i = tid; i < (128 * 40) / 4; i += 256)
        ((float4*)sW)[i] = ((const float4*)Wl)[i];
    if (tid < 40) sB[tid] = bl[tid];
    for (int i = tid; i < 32 * 32; i += 256) {
        int r = i >> 5, cq = i & 31;
        float4 v = make_float4(0.f, 0.f, 0.f, 0.f);
        if (row0 + r < M) v = *(const float4*)&xe[(size_t)(row0 + r) * 128 + cq * 4];
        *(float4*)&sX[r][cq * 4] = v;
    }
    __syncthreads();

    const int g = tid >> 3;  // local row 0..31
    const int l = tid & 7;   // lane-in-row
    const int row = row0 + g;
    float acc[5] = {0.f, 0.f, 0.f, 0.f, 0.f};
    for (int k = 0; k < 128; ++k) {
        float xv = sX[g][k];
        const float* w = &sW[k * 40 + l * 5];
#pragma unroll
        for (int j = 0; j < 5; ++j) acc[j] = fmaf(xv, w[j], acc[j]);
    }
#pragma unroll
    for (int j = 0; j < 5; ++j) acc[j] += sB[l * 5 + j];

    float m = acc[0];
#pragma unroll
    for (int j = 1; j < 5; ++j) m = fmaxf(m, acc[j]);
#pragma unroll
    for (int off = 1; off < 8; off <<= 1) m = fmaxf(m, __shfl_xor(m, off));
    float s = 0.f;
#pragma unroll
    for (int j = 0; j < 5; ++j) s += expf(acc[j] - m);
#pragma unroll
    for (int off = 1; off < 8; off <<= 1) s += __shfl_xor(s, off);
    float lse = m + logf(s);
    if (row < M) {
#pragma unroll
        for (int j = 0; j < 5; ++j) out[(size_t)row * 40 + l * 5 + j] = acc[j] - lse;
    }
}

// ---------------------------------------------------------------------------
// launch
// ---------------------------------------------------------------------------
extern "C" void kernel_launch(void* const* d_in, const int* in_sizes, int n_in,
                              void* d_out, int out_size, void* d_ws, size_t ws_size,
                              hipStream_t stream) {
    const float* x  = (const float*)d_in[0];
    const int*   ei = (const int*)d_in[1];
    const float* W1 = (const float*)d_in[2];
    const float* b1 = (const float*)d_in[3];
    const float* W2 = (const float*)d_in[4];
    const float* b2 = (const float*)d_in[5];
    const float* Wl = (const float*)d_in[6];
    const float* bl = (const float*)d_in[7];

    const int N = in_sizes[0] / FDIM;   // 50000
    const int E = in_sizes[1] / 2;      // 600000
    const int* src = ei;
    const int* dst = ei + E;

    float* out_lsm = (float*)d_out;                    // [N,40]
    float* x_emb   = (float*)d_out + (size_t)N * ODIM; // [N,128]

    // workspace layout
    char* w = (char*)d_ws;
    int* count  = (int*)w;              // N
    int* rowptr = count + N;            // N+1
    int* cursor = rowptr + N + 1;       // N
    int* csr    = cursor + N;           // E
    float* dinv = (float*)(csr + E);    // N
    int* blockSums = (int*)(dinv + N);  // 64
    unsigned short* Wt1 = (unsigned short*)(blockSums + 64);  // 16384 bf16
    unsigned short* Wt2 = Wt1 + 128 * 128;                    // 16384 bf16
    size_t small_bytes = (size_t)4 * ((size_t)N + (N + 1) + N + E + N + 64) + 2 * 128 * 128 * 2;
    size_t off = (small_bytes + 255) & ~(size_t)255;
    unsigned* bufA = (unsigned*)(w + off);       // N*64 uints (g, bf16x2)
    unsigned* bufB = bufA + (size_t)N * 64;      // N*64 uints (h, bf16x2)

    const int nchunk = (N + 1023) / 1024;        // 49 for N=50000 (<=64 required)

    hipMemsetAsync(count, 0, (size_t)N * sizeof(int), stream);
    count_edges_k<<<(E + 255) / 256, 256, 0, stream>>>(dst, count, E);
    block_sum_k<<<nchunk, 256, 0, stream>>>(count, blockSums, dinv, N);
    scan_sums_k<<<1, 64, 0, stream>>>(blockSums, nchunk, rowptr, N);
    scan_chunk_k<<<nchunk, 256, 0, stream>>>(count, blockSums, rowptr, cursor, N);
    fill_csr_k<<<(E + 255) / 256, 256, 0, stream>>>(src, dst, cursor, csr, E);
    convert_wt_k<<<64, 256, 0, stream>>>(W1, Wt1);
    convert_wt_k<<<64, 256, 0, stream>>>(W2, Wt2);

    int gblocks = (N + 63) / 64;
    // layer 1
    mfma_gemm_k<float><<<gblocks, 256, 0, stream>>>(x, Wt1, dinv, (unsigned short*)bufA, N);
    aggregate_k<true, true><<<N, 64, 0, stream>>>(bufA, dinv, rowptr, csr, b1, bufB, N);
    // layer 2
    mfma_gemm_k<unsigned short><<<gblocks, 256, 0, stream>>>(
        (const unsigned short*)bufB, Wt2, dinv, (unsigned short*)bufA, N);
    aggregate_k<false, false><<<N, 64, 0, stream>>>(bufA, dinv, rowptr, csr, b2, x_emb, N);
    // head
    logits_lsm_k<<<(N + 31) / 32, 256, 0, stream>>>(x_emb, Wl, bl, out_lsm, N);
}